// Round 5
// baseline (273.617 us; speedup 1.0000x reference)
//
#include <hip/hip_runtime.h>
#include <cstdint>

// EdgeConv on MI355X.
// msg_e = A[dst] + B[src], A = x@(W1-W2)+b, B = x@W2.
// agg[i] = A[i] + max_{e: dst=i} B[src_e];  out = relu(agg), 0 for isolated nodes.
// GEMM: bf16x3 MFMA (fp32-level accuracy) with W converted in-block.
// CSR build: ONE kernel, 128 co-resident blocks, LDS hist + 3 grid barriers.
// B stored bf16 (2.56MB -> fits per-XCD L2) for the gather.

#define C_CH 128
#define NBLK 128
#define NMAX_LDS 10016

typedef __attribute__((ext_vector_type(8))) short bf16x8;
typedef __attribute__((ext_vector_type(4))) float f32x4;
typedef __attribute__((ext_vector_type(4))) unsigned int u32x4;

static inline size_t align_up(size_t v, size_t a) { return (v + a - 1) & ~(a - 1); }

__device__ inline unsigned f2bf_bits(float f) {  // RNE float->bf16 bits
    unsigned u = __builtin_bit_cast(unsigned, f);
    return (u + 0x7FFFu + ((u >> 16) & 1u)) >> 16;
}

// device-scope grid barrier: monotonic counter, 128 co-resident blocks (LDS-capped
// at 2 blocks/CU, grid=128 <= 256 CUs -> all resident at t=0).
__device__ inline void gridbar(int* bar, int target) {
    __syncthreads();
    if (threadIdx.x == 0) {
        __threadfence();  // agent-scope release of this block's global writes
        atomicAdd(bar, 1);
        while (__hip_atomic_load(bar, __ATOMIC_ACQUIRE, __HIP_MEMORY_SCOPE_AGENT) < target)
            __builtin_amdgcn_s_sleep(2);
    }
    __syncthreads();
}

// ---- K1: MFMA GEMM. Aarr[N][128] = x@(W1-W2)+b (fp32), Bbf[N][128] = bf16(x@W2).
// W converted to bf16 hi/lo tiles in-block (reads are L2-hot, W = 128KB).
__global__ __launch_bounds__(256) void gemm_mfma(const float* __restrict__ x,
                                                 const float* __restrict__ W,
                                                 const float* __restrict__ bias,
                                                 float* __restrict__ Aarr,
                                                 unsigned short* __restrict__ Bbf,
                                                 int Nn) {
    __shared__ unsigned short Wh[64][136];  // stride 272B: 16B-aligned rows, ~2-way bank
    __shared__ unsigned short Wl[64][136];
    int tid = threadIdx.x;
    int col0 = blockIdx.y * 64;
    bool isA = (col0 < C_CH);  // block-uniform
    for (int idx = tid; idx < 64 * 64; idx += 256) {
        int c = idx & 63, k = (idx >> 6) * 2;  // lanes: consecutive c -> coalesced W reads
        int gc = col0 + c;
        float w0, w1;
        if (isA) {
            w0 = W[k * C_CH + gc] - W[(k + C_CH) * C_CH + gc];
            w1 = W[(k + 1) * C_CH + gc] - W[(k + 1 + C_CH) * C_CH + gc];
        } else {
            int g2 = gc - C_CH;
            w0 = W[(k + C_CH) * C_CH + g2];
            w1 = W[(k + 1 + C_CH) * C_CH + g2];
        }
        unsigned h0 = f2bf_bits(w0), h1 = f2bf_bits(w1);
        float hf0 = __builtin_bit_cast(float, h0 << 16);
        float hf1 = __builtin_bit_cast(float, h1 << 16);
        unsigned l0 = f2bf_bits(w0 - hf0), l1 = f2bf_bits(w1 - hf1);
        *(unsigned*)&Wh[c][k] = h0 | (h1 << 16);
        *(unsigned*)&Wl[c][k] = l0 | (l1 << 16);
    }
    __syncthreads();
    int lane = tid & 63, wv = tid >> 6;
    int r0 = blockIdx.x * 64 + wv * 16;
    int arow = min(r0 + (lane & 15), Nn - 1);  // clamped rows guarded at store
    int kgrp = (lane >> 4) * 8;
    f32x4 acc[4] = {};
#pragma unroll
    for (int kk = 0; kk < 4; ++kk) {
        int k0 = kk * 32 + kgrp;
        const float* xp = &x[(size_t)arow * C_CH + k0];
        float4 v0 = *(const float4*)xp;
        float4 v1 = *(const float4*)(xp + 4);
        float vv[8] = {v0.x, v0.y, v0.z, v0.w, v1.x, v1.y, v1.z, v1.w};
        bf16x8 ah, al;
#pragma unroll
        for (int u = 0; u < 8; ++u) {
            unsigned hb = f2bf_bits(vv[u]);
            float hf = __builtin_bit_cast(float, hb << 16);
            ah[u] = (short)hb;
            al[u] = (short)f2bf_bits(vv[u] - hf);
        }
#pragma unroll
        for (int j = 0; j < 4; ++j) {
            int c = j * 16 + (lane & 15);
            bf16x8 bh = *(const bf16x8*)&Wh[c][k0];
            bf16x8 bl = *(const bf16x8*)&Wl[c][k0];
            acc[j] = __builtin_amdgcn_mfma_f32_16x16x32_bf16(ah, bh, acc[j], 0, 0, 0);
            acc[j] = __builtin_amdgcn_mfma_f32_16x16x32_bf16(al, bh, acc[j], 0, 0, 0);
            acc[j] = __builtin_amdgcn_mfma_f32_16x16x32_bf16(ah, bl, acc[j], 0, 0, 0);
        }
    }
#pragma unroll
    for (int j = 0; j < 4; ++j) {
        int gc = col0 + j * 16 + (lane & 15);
        float badd = isA ? bias[gc] : 0.f;
#pragma unroll
        for (int reg = 0; reg < 4; ++reg) {
            int row = r0 + (lane >> 4) * 4 + reg;  // C/D: col=lane&15, row=(lane>>4)*4+reg
            if (row < Nn) {
                if (isA) Aarr[(size_t)row * C_CH + gc] = acc[j][reg] + badd;
                else     Bbf[(size_t)row * C_CH + (gc - C_CH)] =
                             (unsigned short)f2bf_bits(acc[j][reg]);
            }
        }
    }
}

// ---- K2: full CSR build in one kernel: hist -> colscan -> scan -> scatter ----
__global__ __launch_bounds__(256) void csr_k(const int* __restrict__ src,
                                             const int* __restrict__ dst,
                                             int* __restrict__ T,
                                             int* __restrict__ deg,
                                             int* __restrict__ offs,
                                             int* __restrict__ ssrc,
                                             int* __restrict__ bar,
                                             int E_, int Nn, int chunk) {
    __shared__ int ldeg[NMAX_LDS];
    __shared__ int sbase[NMAX_LDS];
    __shared__ int wsum[4];
    int tid = threadIdx.x, b = blockIdx.x;

    // phase 0: per-block LDS histogram of this block's edge chunk
    for (int i = tid; i < Nn; i += 256) ldeg[i] = 0;
    __syncthreads();
    int e0 = b * chunk, e1 = min(e0 + chunk, E_);
    int n4 = (e1 - e0) >> 2;
    const int4* d4p = (const int4*)(dst + e0);
    for (int i = tid; i < n4; i += 256) {
        int4 d = d4p[i];
        atomicAdd(&ldeg[d.x], 1); atomicAdd(&ldeg[d.y], 1);
        atomicAdd(&ldeg[d.z], 1); atomicAdd(&ldeg[d.w], 1);
    }
    for (int i = e0 + n4 * 4 + tid; i < e1; i += 256) atomicAdd(&ldeg[dst[i]], 1);
    __syncthreads();
    int* Tb = T + (size_t)b * Nn;
    for (int i = tid; i < Nn; i += 256) Tb[i] = ldeg[i];
    gridbar(bar, NBLK);

    // phase 1: column scan across blocks -> per-block exclusive base; deg = totals
    int gt = b * 256 + tid;
    if (gt < Nn) {
        int s = 0;
#pragma unroll 8
        for (int bb = 0; bb < NBLK; ++bb) {
            int t = T[(size_t)bb * Nn + gt];
            T[(size_t)bb * Nn + gt] = s;
            s += t;
        }
        deg[gt] = s;
    }
    gridbar(bar, 2 * NBLK);

    // phase 2: block 0 scans deg -> offs (exclusive), offs[Nn] = total
    if (b == 0) {
        const int PER = (NMAX_LDS + 255) / 256;  // 40 -> covers 10240 >= Nn
        int base0 = tid * PER;
        int s = 0;
#pragma unroll
        for (int k = 0; k < PER; ++k) {
            int idx = base0 + k;
            s += (idx < Nn) ? deg[idx] : 0;
        }
        int lane = tid & 63, wid = tid >> 6;
        int pref = s;
#pragma unroll
        for (int off = 1; off < 64; off <<= 1) {
            int t = __shfl_up(pref, off);
            if (lane >= off) pref += t;
        }
        if (lane == 63) wsum[wid] = pref;
        __syncthreads();
        if (tid < 4) {
            int v = wsum[tid];
#pragma unroll
            for (int off = 1; off < 4; off <<= 1) {
                int t = __shfl_up(v, off, 4);
                if (tid >= off) v += t;
            }
            wsum[tid] = v;
        }
        __syncthreads();
        int run = ((wid > 0) ? wsum[wid - 1] : 0) + (pref - s);
#pragma unroll
        for (int k = 0; k < PER; ++k) {
            int idx = base0 + k;
            int v = (idx < Nn) ? deg[idx] : 0;
            if (idx < Nn) offs[idx] = run;
            run += v;
        }
        if (tid == 255) offs[Nn] = run;
    }
    gridbar(bar, 3 * NBLK);

    // phase 3: scatter; all per-edge lookups in LDS (sbase = offs + Tb, rank via ldeg)
    for (int i = tid; i < Nn; i += 256) {
        sbase[i] = offs[i] + Tb[i];
        ldeg[i] = 0;
    }
    __syncthreads();
    const int4* s4p = (const int4*)(src + e0);
    for (int i = tid; i < n4; i += 256) {
        int4 d = d4p[i];
        int4 sv = s4p[i];
        int r;
        r = atomicAdd(&ldeg[d.x], 1); ssrc[sbase[d.x] + r] = sv.x;
        r = atomicAdd(&ldeg[d.y], 1); ssrc[sbase[d.y] + r] = sv.y;
        r = atomicAdd(&ldeg[d.z], 1); ssrc[sbase[d.z] + r] = sv.z;
        r = atomicAdd(&ldeg[d.w], 1); ssrc[sbase[d.w] + r] = sv.w;
    }
    for (int i = e0 + n4 * 4 + tid; i < e1; i += 256) {
        int d = dst[i];
        int r = atomicAdd(&ldeg[d], 1);
        ssrc[sbase[d] + r] = src[i];
    }
}

// ---- K3: per-node segmented max over bf16 B rows + epilogue ----
// 256 threads = 16 groups x 16 lanes; group reads one edge's 256B row (16B/lane),
// unroll 4 -> 64 rows in flight per block.
__global__ __launch_bounds__(256) void node_max(const float* __restrict__ Aarr,
                                                const unsigned short* __restrict__ Bbf,
                                                const int* __restrict__ offs,
                                                const int* __restrict__ ssrc,
                                                float* __restrict__ out, int Nn) {
    int i = blockIdx.x;
    int tid = threadIdx.x;
    int s = offs[i], e = offs[i + 1];
    if (e == s) {  // isolated node -> zeros (block-uniform)
        if (tid < 32) ((float4*)out)[(size_t)i * 32 + tid] = make_float4(0.f, 0.f, 0.f, 0.f);
        return;
    }
    __shared__ int js[256];
    __shared__ float pm[4][16][8];
    int g = tid >> 4;       // group 0..15
    int l16 = tid & 15;
    int cb = l16 * 8;       // 8 channels per lane
    float m[8];
#pragma unroll
    for (int k = 0; k < 8; ++k) m[k] = -INFINITY;
    for (int base = s; base < e; base += 256) {
        __syncthreads();
        js[tid] = ssrc[min(base + tid, e - 1)];
        __syncthreads();
        int cnt = min(256, e - base);
        for (int t = g; t < cnt; t += 64) {
            u32x4 v[4];
#pragma unroll
            for (int u = 0; u < 4; ++u) {
                int idx = min(t + 16 * u, cnt - 1);  // clamp: duplicate edge, max-safe
                v[u] = *(const u32x4*)&Bbf[(size_t)js[idx] * C_CH + cb];
            }
#pragma unroll
            for (int u = 0; u < 4; ++u) {
#pragma unroll
                for (int p = 0; p < 4; ++p) {
                    unsigned w = v[u][p];
                    float f0 = __builtin_bit_cast(float, w << 16);          // even ch
                    float f1 = __builtin_bit_cast(float, w & 0xFFFF0000u);  // odd ch
                    m[2 * p]     = fmaxf(m[2 * p], f0);
                    m[2 * p + 1] = fmaxf(m[2 * p + 1], f1);
                }
            }
        }
    }
#pragma unroll
    for (int k = 0; k < 8; ++k) {  // merge the wave's 4 groups -> lanes 0..15
        m[k] = fmaxf(m[k], __shfl_xor(m[k], 16));
        m[k] = fmaxf(m[k], __shfl_xor(m[k], 32));
    }
    __syncthreads();
    int wid = tid >> 6;
    if ((tid & 63) < 16) {
#pragma unroll
        for (int k = 0; k < 8; ++k) pm[wid][l16][k] = m[k];
    }
    __syncthreads();
    if (tid < C_CH) {
        int c = tid;
        float mm = fmaxf(fmaxf(pm[0][c >> 3][c & 7], pm[1][c >> 3][c & 7]),
                         fmaxf(pm[2][c >> 3][c & 7], pm[3][c >> 3][c & 7]));
        float a = Aarr[(size_t)i * C_CH + c];
        out[(size_t)i * C_CH + c] = fmaxf(a + mm, 0.f);
    }
}

extern "C" void kernel_launch(void* const* d_in, const int* in_sizes, int n_in,
                              void* d_out, int out_size, void* d_ws, size_t ws_size,
                              hipStream_t stream) {
    const float* x = (const float*)d_in[0];   // [N,128]
    const float* W = (const float*)d_in[1];   // [256,128]
    const float* b = (const float*)d_in[2];   // [128]
    const int* src = (const int*)d_in[3];     // [E]
    const int* dst = (const int*)d_in[4];     // [E]
    float* out = (float*)d_out;

    const int N = in_sizes[0] / C_CH;
    const int E = in_sizes[3];
    const int chunk = (((E + NBLK - 1) / NBLK) + 3) & ~3;

    char* w = (char*)d_ws;
    float* Aarr = (float*)w;            w += align_up((size_t)N * C_CH * 4, 256);
    unsigned short* Bbf = (unsigned short*)w;  w += align_up((size_t)N * C_CH * 2, 256);
    int* deg = (int*)w;                 w += align_up((size_t)N * 4, 256);
    int* offs = (int*)w;                w += align_up((size_t)(N + 1) * 4, 256);
    int* T = (int*)w;                   w += align_up((size_t)NBLK * N * 4, 256);
    int* ssrc = (int*)w;                w += align_up((size_t)E * 4, 256);
    int* bar = (int*)w;                 w += 256;

    hipMemsetAsync(bar, 0, 64, stream);

    gemm_mfma<<<dim3((N + 63) / 64, 4), 256, 0, stream>>>(x, W, b, Aarr, Bbf, N);
    csr_k<<<NBLK, 256, 0, stream>>>(src, dst, T, deg, offs, ssrc, bar, E, N, chunk);
    node_max<<<N, 256, 0, stream>>>(Aarr, Bbf, offs, ssrc, out, N);
}

// Round 7
// 147.500 us; speedup vs baseline: 1.8550x; 1.8550x over previous
//
#include <hip/hip_runtime.h>
#include <cstdint>

// EdgeConv on MI355X.
// msg_e = A[dst] + B[src], A = x@(W1-W2)+b, B = x@W2.
// agg[i] = A[i] + max_{e: dst=i} B[src_e];  out = relu(agg), 0 for isolated nodes.
// GEMM: bf16x3 MFMA (fp32-level accuracy), W converted in-block.
// CSR build: 4 small kernels, each at its natural grid size (R5 post-mortem:
// fusing to 128 co-resident blocks = 0.5 blk/CU exposed all latency; unfused
// per-phase TLP is what makes this fast).
// B stored bf16 (2.56MB -> fits per-XCD L2) for the gather.

#define C_CH 128
#define NBLK 128
#define NMAX_LDS 10016

typedef __attribute__((ext_vector_type(8))) short bf16x8;
typedef __attribute__((ext_vector_type(4))) float f32x4;
typedef __attribute__((ext_vector_type(4))) unsigned int u32x4;

static inline size_t align_up(size_t v, size_t a) { return (v + a - 1) & ~(a - 1); }

__device__ inline unsigned f2bf_bits(float f) {  // RNE float->bf16 bits
    unsigned u = __builtin_bit_cast(unsigned, f);
    return (u + 0x7FFFu + ((u >> 16) & 1u)) >> 16;
}

// ---- K1: MFMA GEMM. Aarr[N][128] = x@(W1-W2)+b (fp32), Bbf[N][128] = bf16(x@W2).
__global__ __launch_bounds__(256) void gemm_mfma(const float* __restrict__ x,
                                                 const float* __restrict__ W,
                                                 const float* __restrict__ bias,
                                                 float* __restrict__ Aarr,
                                                 unsigned short* __restrict__ Bbf,
                                                 int Nn) {
    __shared__ unsigned short Wh[64][136];
    __shared__ unsigned short Wl[64][136];
    int tid = threadIdx.x;
    int col0 = blockIdx.y * 64;
    bool isA = (col0 < C_CH);  // block-uniform
    for (int idx = tid; idx < 64 * 64; idx += 256) {
        int c = idx & 63, k = (idx >> 6) * 2;  // consecutive c -> coalesced W reads
        int gc = col0 + c;
        float w0, w1;
        if (isA) {
            w0 = W[k * C_CH + gc] - W[(k + C_CH) * C_CH + gc];
            w1 = W[(k + 1) * C_CH + gc] - W[(k + 1 + C_CH) * C_CH + gc];
        } else {
            int g2 = gc - C_CH;
            w0 = W[(k + C_CH) * C_CH + g2];
            w1 = W[(k + 1 + C_CH) * C_CH + g2];
        }
        unsigned h0 = f2bf_bits(w0), h1 = f2bf_bits(w1);
        float hf0 = __builtin_bit_cast(float, h0 << 16);
        float hf1 = __builtin_bit_cast(float, h1 << 16);
        unsigned l0 = f2bf_bits(w0 - hf0), l1 = f2bf_bits(w1 - hf1);
        *(unsigned*)&Wh[c][k] = h0 | (h1 << 16);
        *(unsigned*)&Wl[c][k] = l0 | (l1 << 16);
    }
    __syncthreads();
    int lane = tid & 63, wv = tid >> 6;
    int r0 = blockIdx.x * 64 + wv * 16;
    int arow = min(r0 + (lane & 15), Nn - 1);
    int kgrp = (lane >> 4) * 8;
    f32x4 acc[4] = {};
#pragma unroll
    for (int kk = 0; kk < 4; ++kk) {
        int k0 = kk * 32 + kgrp;
        const float* xp = &x[(size_t)arow * C_CH + k0];
        float4 v0 = *(const float4*)xp;
        float4 v1 = *(const float4*)(xp + 4);
        float vv[8] = {v0.x, v0.y, v0.z, v0.w, v1.x, v1.y, v1.z, v1.w};
        bf16x8 ah, al;
#pragma unroll
        for (int u = 0; u < 8; ++u) {
            unsigned hb = f2bf_bits(vv[u]);
            float hf = __builtin_bit_cast(float, hb << 16);
            ah[u] = (short)hb;
            al[u] = (short)f2bf_bits(vv[u] - hf);
        }
#pragma unroll
        for (int j = 0; j < 4; ++j) {
            int c = j * 16 + (lane & 15);
            bf16x8 bh = *(const bf16x8*)&Wh[c][k0];
            bf16x8 bl = *(const bf16x8*)&Wl[c][k0];
            acc[j] = __builtin_amdgcn_mfma_f32_16x16x32_bf16(ah, bh, acc[j], 0, 0, 0);
            acc[j] = __builtin_amdgcn_mfma_f32_16x16x32_bf16(al, bh, acc[j], 0, 0, 0);
            acc[j] = __builtin_amdgcn_mfma_f32_16x16x32_bf16(ah, bl, acc[j], 0, 0, 0);
        }
    }
#pragma unroll
    for (int j = 0; j < 4; ++j) {
        int gc = col0 + j * 16 + (lane & 15);
        float badd = isA ? bias[gc] : 0.f;
#pragma unroll
        for (int reg = 0; reg < 4; ++reg) {
            int row = r0 + (lane >> 4) * 4 + reg;  // C/D: col=lane&15, row=(lane>>4)*4+reg
            if (row < Nn) {
                if (isA) Aarr[(size_t)row * C_CH + gc] = acc[j][reg] + badd;
                else     Bbf[(size_t)row * C_CH + (gc - C_CH)] =
                             (unsigned short)f2bf_bits(acc[j][reg]);
            }
        }
    }
}

// ---- K2: per-block LDS histogram of dst -> T[b][n] (coalesced row write) ----
__global__ __launch_bounds__(256) void hist_k(const int* __restrict__ dst,
                                              int* __restrict__ T,
                                              int E_, int Nn, int chunk) {
    __shared__ int ldeg[NMAX_LDS];
    int tid = threadIdx.x, b = blockIdx.x;
    for (int i = tid; i < Nn; i += 256) ldeg[i] = 0;
    __syncthreads();
    int e0 = b * chunk, e1 = min(e0 + chunk, E_);
    int n4 = (e1 - e0) >> 2;
    const int4* d4p = (const int4*)(dst + e0);
    for (int i = tid; i < n4; i += 256) {
        int4 d = d4p[i];
        atomicAdd(&ldeg[d.x], 1); atomicAdd(&ldeg[d.y], 1);
        atomicAdd(&ldeg[d.z], 1); atomicAdd(&ldeg[d.w], 1);
    }
    for (int i = e0 + n4 * 4 + tid; i < e1; i += 256) atomicAdd(&ldeg[dst[i]], 1);
    __syncthreads();
    int* Tb = T + (size_t)b * Nn;
    for (int i = tid; i < Nn; i += 256) Tb[i] = ldeg[i];
}

// ---- K3: column scan of T, one WAVE per node (gather + shfl prefix, max TLP) ----
// lane l holds T[l][n] and T[l+64][n]; 128-elem exclusive prefix in-register.
__global__ __launch_bounds__(256) void colscan_k(int* __restrict__ T,
                                                 int* __restrict__ deg, int Nn) {
    int tid = threadIdx.x;
    int lane = tid & 63;
    int n = blockIdx.x * 4 + (tid >> 6);
    if (n >= Nn) return;  // wave-uniform
    size_t st = (size_t)Nn;
    int e0 = T[lane * st + n];
    int e1 = T[(lane + 64) * st + n];
    int i0 = e0, i1 = e1;
#pragma unroll
    for (int off = 1; off < 64; off <<= 1) {
        int t0 = __shfl_up(i0, off);
        int t1 = __shfl_up(i1, off);
        if (lane >= off) { i0 += t0; i1 += t1; }
    }
    int tot0 = __shfl(i0, 63);
    int tot1 = __shfl(i1, 63);
    T[lane * st + n] = i0 - e0;              // exclusive base, blocks 0..63
    T[(lane + 64) * st + n] = tot0 + i1 - e1;  // blocks 64..127
    if (lane == 0) deg[n] = tot0 + tot1;
}

// ---- K4: exclusive prefix sum over deg -> offs (single block, wave-shuffle) ----
__global__ __launch_bounds__(1024) void scan_k(const int* __restrict__ deg,
                                               int* __restrict__ offs, int n) {
    __shared__ int wsum[16];
    const int PER = 16;
    int tid = threadIdx.x;
    int base = tid * PER;
    int s = 0;
#pragma unroll
    for (int k = 0; k < PER; ++k) {
        int idx = base + k;
        s += (idx < n) ? deg[idx] : 0;
    }
    int lane = tid & 63, wid = tid >> 6;
    int pref = s;
#pragma unroll
    for (int off = 1; off < 64; off <<= 1) {
        int t = __shfl_up(pref, off);
        if (lane >= off) pref += t;
    }
    if (lane == 63) wsum[wid] = pref;
    __syncthreads();
    if (tid < 16) {
        int v = wsum[tid];
#pragma unroll
        for (int off = 1; off < 16; off <<= 1) {
            int t = __shfl_up(v, off, 16);
            if (tid >= off) v += t;
        }
        wsum[tid] = v;
    }
    __syncthreads();
    int run = ((wid > 0) ? wsum[wid - 1] : 0) + (pref - s);
#pragma unroll
    for (int k = 0; k < PER; ++k) {
        int idx = base + k;
        int v = (idx < n) ? deg[idx] : 0;
        if (idx < n) offs[idx] = run;
        run += v;
    }
    if (tid == 1023) offs[n] = run;
}

// ---- K5: scatter into CSR order; sbase = offs + T[b] in LDS, ranks via LDS atomics ----
__global__ __launch_bounds__(256) void scatter_k(const int* __restrict__ src,
                                                 const int* __restrict__ dst,
                                                 const int* __restrict__ T,
                                                 const int* __restrict__ offs,
                                                 int* __restrict__ ssrc,
                                                 int E_, int Nn, int chunk) {
    __shared__ int sbase[NMAX_LDS];
    __shared__ int ldeg[NMAX_LDS];
    int tid = threadIdx.x, b = blockIdx.x;
    const int* Tb = T + (size_t)b * Nn;
    for (int i = tid; i < Nn; i += 256) {
        sbase[i] = offs[i] + Tb[i];
        ldeg[i] = 0;
    }
    __syncthreads();
    int e0 = b * chunk, e1 = min(e0 + chunk, E_);
    int n4 = (e1 - e0) >> 2;
    const int4* d4p = (const int4*)(dst + e0);
    const int4* s4p = (const int4*)(src + e0);
    for (int i = tid; i < n4; i += 256) {
        int4 d = d4p[i];
        int4 sv = s4p[i];
        int r;
        r = atomicAdd(&ldeg[d.x], 1); ssrc[sbase[d.x] + r] = sv.x;
        r = atomicAdd(&ldeg[d.y], 1); ssrc[sbase[d.y] + r] = sv.y;
        r = atomicAdd(&ldeg[d.z], 1); ssrc[sbase[d.z] + r] = sv.z;
        r = atomicAdd(&ldeg[d.w], 1); ssrc[sbase[d.w] + r] = sv.w;
    }
    for (int i = e0 + n4 * 4 + tid; i < e1; i += 256) {
        int d = dst[i];
        int r = atomicAdd(&ldeg[d], 1);
        ssrc[sbase[d] + r] = src[i];
    }
}

// ---- K6: per-node segmented max over bf16 B rows + epilogue ----
__global__ __launch_bounds__(256) void node_max(const float* __restrict__ Aarr,
                                                const unsigned short* __restrict__ Bbf,
                                                const int* __restrict__ offs,
                                                const int* __restrict__ ssrc,
                                                float* __restrict__ out, int Nn) {
    int i = blockIdx.x;
    int tid = threadIdx.x;
    int s = offs[i], e = offs[i + 1];
    if (e == s) {
        if (tid < 32) ((float4*)out)[(size_t)i * 32 + tid] = make_float4(0.f, 0.f, 0.f, 0.f);
        return;
    }
    __shared__ int js[256];
    __shared__ float pm[4][16][8];
    int g = tid >> 4;       // group 0..15
    int l16 = tid & 15;
    int cb = l16 * 8;       // 8 channels per lane
    float m[8];
#pragma unroll
    for (int k = 0; k < 8; ++k) m[k] = -INFINITY;
    for (int base = s; base < e; base += 256) {
        __syncthreads();
        js[tid] = ssrc[min(base + tid, e - 1)];
        __syncthreads();
        int cnt = min(256, e - base);
        for (int t = g; t < cnt; t += 64) {
            u32x4 v[4];
#pragma unroll
            for (int u = 0; u < 4; ++u) {
                int idx = min(t + 16 * u, cnt - 1);  // clamp: duplicate edge, max-safe
                v[u] = *(const u32x4*)&Bbf[(size_t)js[idx] * C_CH + cb];
            }
#pragma unroll
            for (int u = 0; u < 4; ++u) {
#pragma unroll
                for (int p = 0; p < 4; ++p) {
                    unsigned w = v[u][p];
                    float f0 = __builtin_bit_cast(float, w << 16);
                    float f1 = __builtin_bit_cast(float, w & 0xFFFF0000u);
                    m[2 * p]     = fmaxf(m[2 * p], f0);
                    m[2 * p + 1] = fmaxf(m[2 * p + 1], f1);
                }
            }
        }
    }
#pragma unroll
    for (int k = 0; k < 8; ++k) {
        m[k] = fmaxf(m[k], __shfl_xor(m[k], 16));
        m[k] = fmaxf(m[k], __shfl_xor(m[k], 32));
    }
    __syncthreads();
    int wid = tid >> 6;
    if ((tid & 63) < 16) {
#pragma unroll
        for (int k = 0; k < 8; ++k) pm[wid][l16][k] = m[k];
    }
    __syncthreads();
    if (tid < C_CH) {
        int c = tid;
        float mm = fmaxf(fmaxf(pm[0][c >> 3][c & 7], pm[1][c >> 3][c & 7]),
                         fmaxf(pm[2][c >> 3][c & 7], pm[3][c >> 3][c & 7]));
        float a = Aarr[(size_t)i * C_CH + c];
        out[(size_t)i * C_CH + c] = fmaxf(a + mm, 0.f);
    }
}

extern "C" void kernel_launch(void* const* d_in, const int* in_sizes, int n_in,
                              void* d_out, int out_size, void* d_ws, size_t ws_size,
                              hipStream_t stream) {
    const float* x = (const float*)d_in[0];   // [N,128]
    const float* W = (const float*)d_in[1];   // [256,128]
    const float* b = (const float*)d_in[2];   // [128]
    const int* src = (const int*)d_in[3];     // [E]
    const int* dst = (const int*)d_in[4];     // [E]
    float* out = (float*)d_out;

    const int N = in_sizes[0] / C_CH;
    const int E = in_sizes[3];
    const int chunk = (((E + NBLK - 1) / NBLK) + 3) & ~3;

    char* w = (char*)d_ws;
    float* Aarr = (float*)w;            w += align_up((size_t)N * C_CH * 4, 256);
    unsigned short* Bbf = (unsigned short*)w;  w += align_up((size_t)N * C_CH * 2, 256);
    int* deg = (int*)w;                 w += align_up((size_t)N * 4, 256);
    int* offs = (int*)w;                w += align_up((size_t)(N + 1) * 4, 256);
    int* T = (int*)w;                   w += align_up((size_t)NBLK * N * 4, 256);
    int* ssrc = (int*)w;                w += align_up((size_t)E * 4, 256);

    gemm_mfma<<<dim3((N + 63) / 64, 4), 256, 0, stream>>>(x, W, b, Aarr, Bbf, N);
    hist_k<<<NBLK, 256, 0, stream>>>(dst, T, E, N, chunk);
    colscan_k<<<(N + 3) / 4, 256, 0, stream>>>(T, deg, N);
    scan_k<<<1, 1024, 0, stream>>>(deg, offs, N);
    scatter_k<<<NBLK, 256, 0, stream>>>(src, dst, T, offs, ssrc, E, N, chunk);
    node_max<<<N, 256, 0, stream>>>(Aarr, Bbf, offs, ssrc, out, N);
}